// Round 1
// baseline (1754.997 us; speedup 1.0000x reference)
//
#include <hip/hip_runtime.h>
#include <math.h>

#define TT 4096
#define DD 64
#define CC 32
#define KK 20
#define NEGV -1.0e9f
#define L2E 1.44269504088896340736f
#define LN2f 0.69314718055994530942f

#if __has_builtin(__builtin_amdgcn_permlane32_swap)
#define HAVE_PLSWAP 1
#endif
#if __has_builtin(__builtin_amdgcn_permlane16_swap)
#define HAVE_PL16 1
#endif

// ---- static device scratch (no dependence on ws_size) ----
// parameters (log2-units where noted)
__device__ __align__(16) float g_pmu[32 * 64];   // L2E * p_d * mu[c][d]
__device__ __align__(16) float g_p2[64];         // 0.5 * L2E * p_d
__device__ __align__(16) float g_mc[32];         // -0.5*L2E*(muPmu[c] + const)
__device__ __align__(16) float g_ls2[20 * 32];   // L2E * duration scores [k][c]
__device__ __align__(16) float g_T[32 * 32];     // linear transition probs [to][from]
__device__ __align__(16) float g_init2[32];      // L2E * log_softmax(init)
// emissions -> inclusive cumsum, [b][t][c], log2 units
__device__ float g_cum[8 * TT * CC];

// cross-half (lanes 0-31 <-> 32-63) exchange; semantics-agnostic select.
__device__ __forceinline__ float xswap32(float x) {
#ifdef HAVE_PLSWAP
    int xi = __float_as_int(x);
    auto pr = __builtin_amdgcn_permlane32_swap(xi, xi, false, false);
    int r0 = ((const int*)&pr)[0];
    int r1 = ((const int*)&pr)[1];
    // whichever output kept our own value bit-identical, return the other one
    return (r0 == xi) ? __int_as_float(r1) : __int_as_float(r0);
#else
    return __shfl_xor(x, 32);
#endif
}

// row exchange lanes l <-> l^16 (same select trick)
__device__ __forceinline__ float xswap16(float x) {
#ifdef HAVE_PL16
    int xi = __float_as_int(x);
    auto pr = __builtin_amdgcn_permlane16_swap(xi, xi, false, false);
    int r0 = ((const int*)&pr)[0];
    int r1 = ((const int*)&pr)[1];
    return (r0 == xi) ? __int_as_float(r1) : __int_as_float(r0);
#else
    return __shfl_xor(x, 16);
#endif
}

// DPP lane permute within 16-lane rows; only XOR-symmetric patterns used:
//  0xB1 = quad_perm [1,0,3,2]  -> lane i gets i^1
//  0x4E = quad_perm [2,3,0,1]  -> lane i gets i^2
//  0x141 = row_half_mirror     -> lane i gets i^7
//  0x140 = row_mirror          -> lane i gets i^15
#define DPPF(dst, src, CTRL) \
    dst = __int_as_float(__builtin_amdgcn_update_dpp(0, __float_as_int(src), (CTRL), 0xF, 0xF, 1))

// ---------------- setup: tiny, 1 block x 64 ----------------
__global__ void smm_setup(const float* __restrict__ plr,
                          const float* __restrict__ mu,
                          const float* __restrict__ cov,
                          const float* __restrict__ tl,
                          const float* __restrict__ il) {
    int l = threadIdx.x;
    __shared__ float red[64];
    __shared__ float constc_s;
    float cd = cov[l * 64 + l];
    float pd = 1.0f / cd;
    red[l] = logf(cd);
    __syncthreads();
    if (l == 0) {
        float s = 0.f;
        for (int i = 0; i < 64; ++i) s += red[i];
        constc_s = 64.0f * logf(2.0f * 3.14159265358979323846f) + s;
    }
    __syncthreads();
    float constc = constc_s;

    g_p2[l] = 0.5f * L2E * pd;
    for (int c2 = 0; c2 < 32; ++c2)
        g_pmu[c2 * 64 + l] = L2E * pd * mu[c2 * 64 + l];

    if (l < 32) {
        float s = 0.f;
        for (int d2 = 0; d2 < 64; ++d2) {
            float m_ = mu[l * 64 + d2];
            s += m_ * m_ / cov[d2 * 64 + d2];
        }
        g_mc[l] = -0.5f * L2E * (s + constc);
    }
    for (int idx = l; idx < KK * CC; idx += 64) {
        int k = idx >> 5, c2 = idx & 31;
        float lr = plr[c2];
        g_ls2[idx] = L2E * ((float)(k + 1) * lr - expf(lr) - lgammaf((float)(k + 2)));
    }
    if (l < 32) {
        int from = l;
        float mx = -1e30f;
        for (int to = 0; to < 32; ++to) mx = fmaxf(mx, tl[to * 32 + from]);
        float s = 0.f;
        for (int to = 0; to < 32; ++to) s += expf(tl[to * 32 + from] - mx);
        float inv = 1.0f / s;
        for (int to = 0; to < 32; ++to)
            g_T[to * 32 + from] = expf(tl[to * 32 + from] - mx) * inv;
    }
    if (l == 32) {
        float mx = -1e30f;
        for (int c2 = 0; c2 < 32; ++c2) mx = fmaxf(mx, il[c2]);
        float s = 0.f;
        for (int c2 = 0; c2 < 32; ++c2) s += expf(il[c2] - mx);
        float lse = mx + logf(s);
        for (int c2 = 0; c2 < 32; ++c2) g_init2[c2] = L2E * (il[c2] - lse);
    }
}

// ------------- emit: fully parallel, one thread per (t-slice, c) -------------
__global__ __launch_bounds__(256) void smm_emit(const float* __restrict__ feat) {
    int tid = threadIdx.x;
    int c = tid & 31, tl_ = tid >> 5;
    int t = blockIdx.x * 8 + tl_;
    int b = blockIdx.y;
    const float4* x4 = (const float4*)(feat + ((size_t)b * TT + t) * DD);
    const float4* pm4 = (const float4*)(g_pmu + c * 64);
    const float4* p24 = (const float4*)g_p2;
    float acc = g_mc[c];
#pragma unroll
    for (int i = 0; i < 16; ++i) {
        float4 xv = x4[i], pm = pm4[i], pv = p24[i];
        acc = fmaf(pm.x, xv.x, acc); acc = fmaf(-pv.x * xv.x, xv.x, acc);
        acc = fmaf(pm.y, xv.y, acc); acc = fmaf(-pv.y * xv.y, xv.y, acc);
        acc = fmaf(pm.z, xv.z, acc); acc = fmaf(-pv.z * xv.z, xv.z, acc);
        acc = fmaf(pm.w, xv.w, acc); acc = fmaf(-pv.w * xv.w, xv.w, acc);
    }
    g_cum[((size_t)b * TT + t) * CC + c] = acc;
}

// ------------- scan: in-place inclusive cumsum over t, per (b,c) -------------
__global__ __launch_bounds__(256) void smm_scan() {
    int b = blockIdx.x;
    int tid = threadIdx.x;
    int c = tid & 31, g = tid >> 5;          // 8 groups x 512 t's
    float* base = g_cum + (size_t)b * TT * CC + c;
    int t0 = g * 512;
    float run = 0.f;
    for (int t = t0; t < t0 + 512; t += 8) {
        float v[8];
#pragma unroll
        for (int j = 0; j < 8; ++j) v[j] = base[(size_t)(t + j) * CC];
#pragma unroll
        for (int j = 0; j < 8; ++j) { run += v[j]; base[(size_t)(t + j) * CC] = run; }
    }
    __shared__ float tot[8][32];
    tot[g][c] = run;
    __syncthreads();
    float pre = 0.f;
#pragma unroll
    for (int gg = 0; gg < 7; ++gg) if (gg < g) pre += tot[gg][c];
    if (g > 0) {
        for (int t = t0; t < t0 + 512; t += 8) {
            float v[8];
#pragma unroll
            for (int j = 0; j < 8; ++j) v[j] = base[(size_t)(t + j) * CC];
#pragma unroll
            for (int j = 0; j < 8; ++j) base[(size_t)(t + j) * CC] = v[j] + pre;
        }
    }
}

// ------------- forward recursion: one wave per b, everything log2-units -------------
// Carried per-step state besides hb[]/cr[]:
//   vn0  = next step's v0 (hb[0]+lsr[0]), forwarded from astar with 1-op depth
//   Rg   = max over v1..v9 of BOTH halves for the NEXT step (known a full step early)
//   sRg  = sum over both halves of exp2(v_i - Rg), i=1..9, for the NEXT step
// so the serial chain per step is only: v0 -> m -> e0/eR -> sk -> pf -> DPP gather
// -> fma tree -> log2 -> astar.  No LDS anywhere.
#define STEP(j, tcur)                                                              \
    {                                                                              \
        float cum2 = cr[j];                                                        \
        int tp = (tcur) + 8; if (tp > TT - 1) tp = TT - 1;                         \
        cr[j] = cumb[(size_t)tp * CC];                                             \
        /* ---- precompute NEXT step's Rg/sRg: uses hb[0..8] (pre-shift), which */ \
        /* depends only on astar(t-1) -> schedulable under this step's tail.    */ \
        float nv1 = hb[0] + lsr[1], nv2 = hb[1] + lsr[2], nv3 = hb[2] + lsr[3],    \
              nv4 = hb[3] + lsr[4], nv5 = hb[4] + lsr[5], nv6 = hb[5] + lsr[6],    \
              nv7 = hb[6] + lsr[7], nv8 = hb[7] + lsr[8], nv9 = hb[8] + lsr[9];    \
        float nRA = fmaxf(fmaxf(nv1, nv2), nv3);                                   \
        float nRB = fmaxf(fmaxf(nv4, nv5), nv6);                                   \
        float nRC = fmaxf(fmaxf(nv7, nv8), nv9);                                   \
        float nR  = fmaxf(fmaxf(nRA, nRB), nRC);                                   \
        float nRg = fmaxf(nR, xswap32(nR));                                        \
        float f1 = exp2f(nv1 - nRg), f2 = exp2f(nv2 - nRg), f3 = exp2f(nv3 - nRg), \
              f4 = exp2f(nv4 - nRg), f5 = exp2f(nv5 - nRg), f6 = exp2f(nv6 - nRg), \
              f7 = exp2f(nv7 - nRg), f8 = exp2f(nv8 - nRg), f9 = exp2f(nv9 - nRg); \
        float nsR = (((f1 + f2) + (f3 + f4)) + ((f5 + f6) + (f7 + f8))) + f9;      \
        float nsRg = nsR + xswap32(nsR);                                           \
        /* ---- critical path ---- */                                              \
        float v0  = vn0;                                                           \
        float v0m = fmaxf(v0, xswap32(v0));                                        \
        float m   = fmaxf(v0m, Rg);                                                \
        float e0o = exp2f(v0 - m);                                                 \
        float eR  = exp2f(Rg - m);                                                 \
        float e0x = xswap32(e0o);                                                  \
        float sk  = fmaf(sRg, eR, e0o + e0x);                                      \
        float base = cum2 + m;                                                     \
        float refs = __int_as_float(__builtin_amdgcn_readfirstlane(__float_as_int(base))); \
        float pf = sk * exp2f((base - refs) - 64.0f);                              \
        /* XOR all-gather of the 16 p-values of this lane's row */                 \
        float G1, G2, G3, G4, G5, G6, G7, G8, G9, G10, G11, G12, G13, G14, G15;    \
        DPPF(G1,  pf, 0xB1);                                                       \
        DPPF(G2,  pf, 0x4E);  DPPF(G3,  G1, 0x4E);                                 \
        DPPF(G7,  pf, 0x141); DPPF(G6,  G1, 0x141);                                \
        DPPF(G5,  G2, 0x141); DPPF(G4,  G3, 0x141);                                \
        DPPF(G15, pf, 0x140); DPPF(G14, G1, 0x140);                                \
        DPPF(G13, G2, 0x140); DPPF(G12, G3, 0x140);                                \
        DPPF(G11, G4, 0x140); DPPF(G10, G5, 0x140);                                \
        DPPF(G9,  G6, 0x140); DPPF(G8,  G7, 0x140);                                \
        float a0 = Tr[0]  * pf;  a0 = fmaf(Tr[1],  G1,  a0);                       \
        a0 = fmaf(Tr[2],  G2,  a0);  a0 = fmaf(Tr[3],  G3,  a0);                   \
        float a1 = Tr[4]  * G4;  a1 = fmaf(Tr[5],  G5,  a1);                       \
        a1 = fmaf(Tr[6],  G6,  a1);  a1 = fmaf(Tr[7],  G7,  a1);                   \
        float a2 = Tr[8]  * G8;  a2 = fmaf(Tr[9],  G9,  a2);                       \
        a2 = fmaf(Tr[10], G10, a2);  a2 = fmaf(Tr[11], G11, a2);                   \
        float a3 = Tr[12] * G12; a3 = fmaf(Tr[13], G13, a3);                       \
        a3 = fmaf(Tr[14], G14, a3);  a3 = fmaf(Tr[15], G15, a3);                   \
        float accl = (a0 + a1) + (a2 + a3);                                        \
        /* combine complementary partial (same class) held by lane l^48 */         \
        float p48  = xswap16(xswap32(accl));                                       \
        float accf = accl + p48;                                                   \
        float astar2 = (refs + 64.0f) + log2f(accf);                               \
        if ((tcur) == len - 1) {                                                   \
            float m2 = base + log2f(sk), s2 = 1.0f;                                \
            _Pragma("unroll")                                                      \
            for (int st = 1; st < 32; st <<= 1) {                                  \
                float om = __shfl_xor(m2, st), os = __shfl_xor(s2, st);            \
                float M = fmaxf(m2, om);                                           \
                s2 = s2 * exp2f(m2 - M) + os * exp2f(om - M);                      \
                m2 = M;                                                            \
            }                                                                      \
            if (l == 0) out[b] = -LN2f * (m2 + log2f(s2));                         \
        }                                                                          \
        float pre0   = lsr[0] - cum2;                                              \
        float hnewN  = astar2 - cum2;                                              \
        float cross9 = xswap32(hb[9]);                                             \
        hb[9]=hb[8]; hb[8]=hb[7]; hb[7]=hb[6]; hb[6]=hb[5]; hb[5]=hb[4];           \
        hb[4]=hb[3]; hb[3]=hb[2]; hb[2]=hb[1]; hb[1]=hb[0];                        \
        hb[0] = half ? cross9 : hnewN;                                             \
        vn0   = half ? (cross9 + lsr[0]) : (astar2 + pre0);                        \
        Rg = nRg; sRg = nsRg;                                                      \
    }

__global__ __launch_bounds__(64, 1)
void smm_forward(const int* __restrict__ lens, float* __restrict__ out) {
    const int b = blockIdx.x;
    const int l = threadIdx.x;
    const int c = l & 31;
    const int half = l >> 5;
    const int i16 = l & 15;
    const int rb = ((l >> 4) & 1) * 16;        // from-range base = this row's content
    const int cT = half ? (c ^ 16) : c;        // upper half computes partner class's partial

    float lsr[10];
#pragma unroll
    for (int i = 0; i < 10; ++i) lsr[i] = g_ls2[(half * 10 + i) * 32 + c];

    // transition row, permuted to match the XOR gather: Tr[j] pairs with p[rb + (i16^j)]
    float Tr[16];
#pragma unroll
    for (int j2 = 0; j2 < 16; ++j2) Tr[j2] = g_T[cT * 32 + rb + (i16 ^ j2)];

    float hb[10];
#pragma unroll
    for (int i = 0; i < 10; ++i) hb[i] = NEGV;
    if (half == 0) hb[0] = g_init2[c];

    int len = lens[b];
    if (len < 1) len = 1;
    if (len > TT) len = TT;
    int nsteps = (len + 7) & ~7;

    const float* cumb = g_cum + (size_t)b * TT * CC + c;
    float cr[8];
#pragma unroll
    for (int j2 = 0; j2 < 8; ++j2) cr[j2] = cumb[(size_t)j2 * CC];

    // bootstrap carried state for the first step (t=0): v_i from initial hb[1..9]
    float vn0 = hb[0] + lsr[0];
    float Rg, sRg;
    {
        float nv1 = hb[1] + lsr[1], nv2 = hb[2] + lsr[2], nv3 = hb[3] + lsr[3],
              nv4 = hb[4] + lsr[4], nv5 = hb[5] + lsr[5], nv6 = hb[6] + lsr[6],
              nv7 = hb[7] + lsr[7], nv8 = hb[8] + lsr[8], nv9 = hb[9] + lsr[9];
        float RA = fmaxf(fmaxf(nv1, nv2), nv3);
        float RB = fmaxf(fmaxf(nv4, nv5), nv6);
        float RC = fmaxf(fmaxf(nv7, nv8), nv9);
        float R  = fmaxf(fmaxf(RA, RB), RC);
        Rg = fmaxf(R, xswap32(R));
        float f1 = exp2f(nv1 - Rg), f2 = exp2f(nv2 - Rg), f3 = exp2f(nv3 - Rg),
              f4 = exp2f(nv4 - Rg), f5 = exp2f(nv5 - Rg), f6 = exp2f(nv6 - Rg),
              f7 = exp2f(nv7 - Rg), f8 = exp2f(nv8 - Rg), f9 = exp2f(nv9 - Rg);
        float sR = (((f1 + f2) + (f3 + f4)) + ((f5 + f6) + (f7 + f8))) + f9;
        sRg = sR + xswap32(sR);
    }

    for (int tb = 0; tb < nsteps; tb += 8) {
        STEP(0, tb + 0); STEP(1, tb + 1); STEP(2, tb + 2); STEP(3, tb + 3);
        STEP(4, tb + 4); STEP(5, tb + 5); STEP(6, tb + 6); STEP(7, tb + 7);
    }
}

extern "C" void kernel_launch(void* const* d_in, const int* in_sizes, int n_in,
                              void* d_out, int out_size, void* d_ws, size_t ws_size,
                              hipStream_t stream) {
    const float* feat = (const float*)d_in[0];
    const float* plr  = (const float*)d_in[1];
    const float* mu   = (const float*)d_in[2];
    const float* cov  = (const float*)d_in[3];
    const float* tl   = (const float*)d_in[4];
    const float* il   = (const float*)d_in[5];
    const int*   lens = (const int*)d_in[6];
    float* outf = (float*)d_out;
    int B = in_sizes[6];
    if (B > 8) B = 8;  // g_cum sized for the problem's B=8

    smm_setup<<<1, 64, 0, stream>>>(plr, mu, cov, tl, il);
    smm_emit<<<dim3(TT / 8, B), 256, 0, stream>>>(feat);
    smm_scan<<<B, 256, 0, stream>>>();
    smm_forward<<<B, 64, 0, stream>>>(lens, outf);
}

// Round 2
// 828.979 us; speedup vs baseline: 2.1171x; 2.1171x over previous
//
#include <hip/hip_runtime.h>
#include <math.h>

#define TT 4096
#define DD 64
#define CC 32
#define KK 20
#define TP 4112   /* transposed row stride: 4096 + 16 pad for prefetch overrun */
#define NEGV -1.0e9f
#define L2E 1.44269504088896340736f
#define LN2f 0.69314718055994530942f

#if __has_builtin(__builtin_amdgcn_permlane32_swap)
#define HAVE_PLSWAP 1
#endif
#if __has_builtin(__builtin_amdgcn_permlane16_swap)
#define HAVE_PL16 1
#endif

// ---- static device scratch ----
__device__ __align__(16) float g_pmu[32 * 64];   // L2E * p_d * mu[c][d]
__device__ __align__(16) float g_p2[64];         // 0.5 * L2E * p_d
__device__ __align__(16) float g_mc[32];         // -0.5*L2E*(muPmu[c] + const)
__device__ __align__(16) float g_ls2[20 * 32];   // L2E * duration scores [k][c]
__device__ __align__(16) float g_T[32 * 32];     // linear transition probs [to][from]
__device__ __align__(16) float g_init2[32];      // L2E * log_softmax(init)
__device__ float g_cum[8 * TT * CC];             // [b][t][c] emissions -> cumsum (log2)
__device__ __align__(16) float g_cumT[8 * 32 * TP]; // [b][c][t] transposed cumsum (log2)

// raw hardware transcendentals (v_exp_f32 / v_log_f32), no libm wrappers
__device__ __forceinline__ float fexp2(float x) {
#if __has_builtin(__builtin_amdgcn_exp2f)
    return __builtin_amdgcn_exp2f(x);
#else
    return __exp2f(x);
#endif
}
__device__ __forceinline__ float flog2(float x) {
#if __has_builtin(__builtin_amdgcn_logf)
    return __builtin_amdgcn_logf(x);
#else
    return __log2f(x);
#endif
}

#define RF(x) __int_as_float(__builtin_amdgcn_readfirstlane(__float_as_int(x)))

// cross-half (lanes 0-31 <-> 32-63) exchange; semantics-agnostic select.
__device__ __forceinline__ float xswap32(float x) {
#ifdef HAVE_PLSWAP
    int xi = __float_as_int(x);
    auto pr = __builtin_amdgcn_permlane32_swap(xi, xi, false, false);
    int r0 = ((const int*)&pr)[0];
    int r1 = ((const int*)&pr)[1];
    return (r0 == xi) ? __int_as_float(r1) : __int_as_float(r0);
#else
    return __shfl_xor(x, 32);
#endif
}

// row exchange lanes l <-> l^16
__device__ __forceinline__ float xswap16(float x) {
#ifdef HAVE_PL16
    int xi = __float_as_int(x);
    auto pr = __builtin_amdgcn_permlane16_swap(xi, xi, false, false);
    int r0 = ((const int*)&pr)[0];
    int r1 = ((const int*)&pr)[1];
    return (r0 == xi) ? __int_as_float(r1) : __int_as_float(r0);
#else
    return __shfl_xor(x, 16);
#endif
}

// XOR-symmetric DPP patterns: 0xB1=xor1, 0x4E=xor2, 0x141=xor7, 0x140=xor15
#define DPPF(dst, src, CTRL) \
    dst = __int_as_float(__builtin_amdgcn_update_dpp(0, __float_as_int(src), (CTRL), 0xF, 0xF, 1))

// ---------------- setup: tiny, 1 block x 64 ----------------
__global__ void smm_setup(const float* __restrict__ plr,
                          const float* __restrict__ mu,
                          const float* __restrict__ cov,
                          const float* __restrict__ tl,
                          const float* __restrict__ il) {
    int l = threadIdx.x;
    __shared__ float red[64];
    __shared__ float constc_s;
    float cd = cov[l * 64 + l];
    float pd = 1.0f / cd;
    red[l] = logf(cd);
    __syncthreads();
    if (l == 0) {
        float s = 0.f;
        for (int i = 0; i < 64; ++i) s += red[i];
        constc_s = 64.0f * logf(2.0f * 3.14159265358979323846f) + s;
    }
    __syncthreads();
    float constc = constc_s;

    g_p2[l] = 0.5f * L2E * pd;
    for (int c2 = 0; c2 < 32; ++c2)
        g_pmu[c2 * 64 + l] = L2E * pd * mu[c2 * 64 + l];

    if (l < 32) {
        float s = 0.f;
        for (int d2 = 0; d2 < 64; ++d2) {
            float m_ = mu[l * 64 + d2];
            s += m_ * m_ / cov[d2 * 64 + d2];
        }
        g_mc[l] = -0.5f * L2E * (s + constc);
    }
    for (int idx = l; idx < KK * CC; idx += 64) {
        int k = idx >> 5, c2 = idx & 31;
        float lr = plr[c2];
        g_ls2[idx] = L2E * ((float)(k + 1) * lr - expf(lr) - lgammaf((float)(k + 2)));
    }
    if (l < 32) {
        int from = l;
        float mx = -1e30f;
        for (int to = 0; to < 32; ++to) mx = fmaxf(mx, tl[to * 32 + from]);
        float s = 0.f;
        for (int to = 0; to < 32; ++to) s += expf(tl[to * 32 + from] - mx);
        float inv = 1.0f / s;
        for (int to = 0; to < 32; ++to)
            g_T[to * 32 + from] = expf(tl[to * 32 + from] - mx) * inv;
    }
    if (l == 32) {
        float mx = -1e30f;
        for (int c2 = 0; c2 < 32; ++c2) mx = fmaxf(mx, il[c2]);
        float s = 0.f;
        for (int c2 = 0; c2 < 32; ++c2) s += expf(il[c2] - mx);
        float lse = mx + logf(s);
        for (int c2 = 0; c2 < 32; ++c2) g_init2[c2] = L2E * (il[c2] - lse);
    }
}

// ------------- emit: one thread per (t-slice, c) -------------
__global__ __launch_bounds__(256) void smm_emit(const float* __restrict__ feat) {
    int tid = threadIdx.x;
    int c = tid & 31, tl_ = tid >> 5;
    int t = blockIdx.x * 8 + tl_;
    int b = blockIdx.y;
    const float4* x4 = (const float4*)(feat + ((size_t)b * TT + t) * DD);
    const float4* pm4 = (const float4*)(g_pmu + c * 64);
    const float4* p24 = (const float4*)g_p2;
    float acc = g_mc[c];
#pragma unroll
    for (int i = 0; i < 16; ++i) {
        float4 xv = x4[i], pm = pm4[i], pv = p24[i];
        acc = fmaf(pm.x, xv.x, acc); acc = fmaf(-pv.x * xv.x, xv.x, acc);
        acc = fmaf(pm.y, xv.y, acc); acc = fmaf(-pv.y * xv.y, xv.y, acc);
        acc = fmaf(pm.z, xv.z, acc); acc = fmaf(-pv.z * xv.z, xv.z, acc);
        acc = fmaf(pm.w, xv.w, acc); acc = fmaf(-pv.w * xv.w, xv.w, acc);
    }
    g_cum[((size_t)b * TT + t) * CC + c] = acc;
}

// ------------- scan: cumsum over t per (b,c); writes transposed [b][c][t] -------------
__global__ __launch_bounds__(256) void smm_scan() {
    int b = blockIdx.x;
    int tid = threadIdx.x;
    int c = tid & 31, g = tid >> 5;          // 8 groups x 512 t's
    float* base = g_cum + (size_t)b * TT * CC + c;
    float* outT = g_cumT + ((size_t)b * 32 + c) * TP;
    int t0 = g * 512;
    float run = 0.f;
    for (int t = t0; t < t0 + 512; t += 8) {
        float v[8];
#pragma unroll
        for (int j = 0; j < 8; ++j) v[j] = base[(size_t)(t + j) * CC];
#pragma unroll
        for (int j = 0; j < 8; ++j) { run += v[j]; base[(size_t)(t + j) * CC] = run; }
    }
    __shared__ float tot[8][32];
    tot[g][c] = run;
    __syncthreads();
    float pre = 0.f;
#pragma unroll
    for (int gg = 0; gg < 7; ++gg) if (gg < g) pre += tot[gg][c];
    for (int t = t0; t < t0 + 512; t += 8) {
        float v[8];
#pragma unroll
        for (int j = 0; j < 8; ++j) v[j] = base[(size_t)(t + j) * CC] + pre;
        float4 w0, w1;
        w0.x = v[0]; w0.y = v[1]; w0.z = v[2]; w0.w = v[3];
        w1.x = v[4]; w1.y = v[5]; w1.z = v[6]; w1.w = v[7];
        *(float4*)(outT + t) = w0;
        *(float4*)(outT + t + 4) = w1;
    }
}

// ------------- forward recursion: one wave per b -------------
// Duration slots carried in SCALED PROBABILITY domain (scale = 2^-(refc+64)):
//   pf   = scaled alpha_t        (identical at both half-lanes of a class)
//   accf = scaled astar_t        (after T-gather)
//   q1..q9 = duration slots d=2..10 (half0) / d=12..20 (half1)
//   u (=accf*nu) = d=1 newborn; Wc = d=11 newborn (cross-half)
// Shift law: slot_i(t+1) = slot_{i-1}(t) * rho[i-1] * sg,  rho const, sg per-step rescale.
// Scale anchor refc tracked with a 2-step-lagged readfirstlane(pf) feedback, so lane0's
// pf stays pinned near 2^-64; everything stays in normal float range.
#define STEP(CUMV, CUMNEXT, tcur)                                                \
    {                                                                            \
        /* ===== critical chain: pf -> DPP gather -> 32x32 matvec -> accf ===== */ \
        float pf = fmaf(accf, nu, OFF);                                          \
        float g1,g2,g3,g4,g5,g6,g7,g8,g9,g10,g11,g12,g13,g14,g15;                \
        DPPF(g1,  pf, 0xB1);                                                     \
        DPPF(g2,  pf, 0x4E);  DPPF(g3,  g1, 0x4E);                               \
        DPPF(g7,  pf, 0x141); DPPF(g6,  g1, 0x141);                              \
        DPPF(g5,  g2, 0x141); DPPF(g4,  g3, 0x141);                              \
        DPPF(g15, pf, 0x140); DPPF(g14, g1, 0x140);                              \
        DPPF(g13, g2, 0x140); DPPF(g12, g3, 0x140);                              \
        DPPF(g11, g4, 0x140); DPPF(g10, g5, 0x140);                              \
        DPPF(g9,  g6, 0x140); DPPF(g8,  g7, 0x140);                              \
        float a0 = Tr[0]*pf;   a0 = fmaf(Tr[1], g1, a0);  a0 = fmaf(Tr[2], g2, a0);  a0 = fmaf(Tr[3], g3, a0); \
        float a1 = Tr[4]*g4;   a1 = fmaf(Tr[5], g5, a1);  a1 = fmaf(Tr[6], g6, a1);  a1 = fmaf(Tr[7], g7, a1); \
        float a2 = Tr[8]*g8;   a2 = fmaf(Tr[9], g9, a2);  a2 = fmaf(Tr[10],g10,a2);  a2 = fmaf(Tr[11],g11,a2); \
        float a3 = Tr[12]*g12; a3 = fmaf(Tr[13],g13,a3);  a3 = fmaf(Tr[14],g14,a3);  a3 = fmaf(Tr[15],g15,a3); \
        float accl = (a0 + a1) + (a2 + a3);                                      \
        float p48  = xswap16(xswap32(accl));                                     \
        float naccf = fmaxf(accl + p48, 1e-30f);                                 \
        /* ===== capture alpha at len-1 ===== */                                 \
        pfL  = ((tcur) == lenm1) ? pf   : pfL;                                   \
        refL = ((tcur) == lenm1) ? refc : refL;                                  \
        /* ===== anchor: ref for t+1 (2-step-lagged feedback, off-chain) ===== */ \
        float aL   = rfc64p + flog2(fmaxf(RF(pfPrev), 1e-37f));                  \
        float rcN  = RF(CUMNEXT);                                                \
        float refn = aL + (rcN - rcPrev);                                        \
        float cKn  = (CUMNEXT - refn) - 64.0f;                                   \
        float sg   = fexp2(cKn - cK);                                            \
        float nun  = sg * E1;                                                    \
        /* ===== duration-slot shift (all multiplies, off-chain) ===== */        \
        float u2   = accf * nu;                                                  \
        float s0   = half ? Wc : u2;                                             \
        float t9   = (q9 * rxr) * sg;                                            \
        float x9   = xswap32(t9);                                                \
        float Wn   = half ? x9 : t9;                                             \
        q9 = (q8*rho[8])*sg; q8 = (q7*rho[7])*sg; q7 = (q6*rho[6])*sg;           \
        q6 = (q5*rho[5])*sg; q5 = (q4*rho[4])*sg; q4 = (q3*rho[3])*sg;           \
        q3 = (q2*rho[2])*sg; q2 = (q1*rho[1])*sg; q1 = (s0*rho[0])*sg;           \
        float S = (((q1+q2)+(q3+q4)) + ((q5+q6)+(q7+q8))) + q9;                  \
        float OFFn = (S + xswap32(S)) + Wn;                                      \
        /* ===== rotate carried state ===== */                                   \
        rfc64p = refc + 64.0f;                                                   \
        rcPrev = RF(CUMV);                                                       \
        pfPrev = pf;                                                             \
        Wc = Wn; accf = naccf; nu = nun; OFF = OFFn; cK = cKn; refc = refn;      \
    }

__global__ __launch_bounds__(64, 1)
void smm_forward(const int* __restrict__ lens, float* __restrict__ out) {
    const int b = blockIdx.x;
    const int l = threadIdx.x;
    const int c = l & 31;
    const int half = l >> 5;
    const int i16 = l & 15;
    const int rb = ((l >> 4) & 1) * 16;
    const int cT = half ? (c ^ 16) : c;

    float lsr[10];
#pragma unroll
    for (int i = 0; i < 10; ++i) lsr[i] = g_ls2[(half * 10 + i) * 32 + c];

    // transition row, permuted for the XOR gather: Tr[j] pairs with p[rb + (i16^j)]
    float Tr[16];
#pragma unroll
    for (int j2 = 0; j2 < 16; ++j2) Tr[j2] = g_T[cT * 32 + rb + (i16 ^ j2)];

    // cross-half duration-score exchange
    float tswp = xswap32(lsr[0]);
    float ls1c = half ? tswp : lsr[0];   // d=1 score of this class (both halves)
    float d11s = half ? lsr[0] : tswp;   // d=11 score of this class

    float rho[9];
#pragma unroll
    for (int i = 0; i < 9; ++i) rho[i] = fexp2(lsr[i + 1] - lsr[i]);
    float rxr = fexp2(d11s - lsr[9]);    // d=10 -> d=11 ratio (meaningful at half0)
    float E1  = fexp2(ls1c);

    int len = lens[b];
    if (len < 1) len = 1;
    if (len > TT) len = TT;
    const int lenm1 = len - 1;
    int nsteps = (len + 7) & ~7;

    const float* cumbT = g_cumT + ((size_t)b * 32 + c) * TP;
    const float4* cp = (const float4*)cumbT;
    float4 cA = cp[0], cB = cp[1], pA = cp[2], pB = cp[3];

    // ---- bootstrap (t = 0): only d=1 newborn from init is live ----
    float q1=0.f,q2=0.f,q3=0.f,q4=0.f,q5=0.f,q6=0.f,q7=0.f,q8=0.f,q9=0.f;
    float Wc = 0.f;
    float iv   = g_init2[c] + ls1c;
    float refc = RF(cA.x + iv);
    float cK   = (cA.x - refc) - 64.0f;
    float nu   = fexp2(iv + cK);
    float accf = 1.0f, OFF = 0.0f;
    float rfc64p = refc + 64.0f;
    float pfPrev = 5.421010862427522e-20f;  // 2^-64 -> first anchor == refc
    float rcPrev = RF(cA.x);
    float pfL = 0.0f, refL = 0.0f;

    for (int tb = 0; tb < nsteps; tb += 8) {
        int bi = tb >> 2;
        float4 nA = cp[bi + 4], nB = cp[bi + 5];   // prefetch t+16..t+23
        STEP(cA.x, cA.y, tb + 0); STEP(cA.y, cA.z, tb + 1);
        STEP(cA.z, cA.w, tb + 2); STEP(cA.w, cB.x, tb + 3);
        STEP(cB.x, cB.y, tb + 4); STEP(cB.y, cB.z, tb + 5);
        STEP(cB.z, cB.w, tb + 6); STEP(cB.w, pA.x, tb + 7);
        cA = pA; cB = pB; pA = nA; pB = nB;
    }

    // ---- final LSE over classes ----
    float alpha2 = refL + 64.0f + flog2(fmaxf(pfL, 1e-37f));
    float m2 = alpha2, s2 = 1.0f;
#pragma unroll
    for (int st = 1; st < 32; st <<= 1) {
        float om = __shfl_xor(m2, st), os = __shfl_xor(s2, st);
        float M = fmaxf(m2, om);
        s2 = s2 * fexp2(m2 - M) + os * fexp2(om - M);
        m2 = M;
    }
    if (l == 0) out[b] = -LN2f * (m2 + flog2(s2));
}

extern "C" void kernel_launch(void* const* d_in, const int* in_sizes, int n_in,
                              void* d_out, int out_size, void* d_ws, size_t ws_size,
                              hipStream_t stream) {
    const float* feat = (const float*)d_in[0];
    const float* plr  = (const float*)d_in[1];
    const float* mu   = (const float*)d_in[2];
    const float* cov  = (const float*)d_in[3];
    const float* tl   = (const float*)d_in[4];
    const float* il   = (const float*)d_in[5];
    const int*   lens = (const int*)d_in[6];
    float* outf = (float*)d_out;
    int B = in_sizes[6];
    if (B > 8) B = 8;  // scratch sized for the problem's B=8

    smm_setup<<<1, 64, 0, stream>>>(plr, mu, cov, tl, il);
    smm_emit<<<dim3(TT / 8, B), 256, 0, stream>>>(feat);
    smm_scan<<<B, 256, 0, stream>>>();
    smm_forward<<<B, 64, 0, stream>>>(lens, outf);
}

// Round 4
// 680.347 us; speedup vs baseline: 2.5796x; 1.2185x over previous
//
#include <hip/hip_runtime.h>
#include <math.h>

#define TT 4096
#define DD 64
#define CC 32
#define KK 20
#define TPE 4128   /* transposed eT row stride: 4096 + 32 pad for prefetch overrun */
#define L2E 1.44269504088896340736f
#define LN2f 0.69314718055994530942f
#define PIN 20.0f  /* lane0 pf pinned near 2^-PIN (symmetric float headroom) */

#if __has_builtin(__builtin_amdgcn_permlane32_swap)
#define HAVE_PLSWAP 1
#endif
#if __has_builtin(__builtin_amdgcn_permlane16_swap)
#define HAVE_PL16 1
#endif

// ---- static device scratch ----
__device__ __align__(16) float g_pmu[32 * 64];   // L2E * p_d * mu[c][d]
__device__ __align__(16) float g_p2[64];         // 0.5 * L2E * p_d
__device__ __align__(16) float g_mc[32];         // -0.5*L2E*(muPmu[c] + const)
__device__ __align__(16) float g_ls2[20 * 32];   // L2E * duration scores [k][c]
__device__ __align__(16) float g_T[32 * 32];     // linear transition probs [to][from]
__device__ __align__(16) float g_init2[32];      // L2E * log_softmax(init)
__device__ float g_mb;                           // analytic mean log2-emission estimate
// eT[b][c][t] = exp2(emit2(b,t+1,c) - mb); slot TT-1 holds exp2(emit2(b,0,c)-mb)
__device__ __align__(16) float g_eT[8 * 32 * TPE];

// raw hardware transcendentals (v_exp_f32 / v_log_f32)
__device__ __forceinline__ float fexp2(float x) {
#if __has_builtin(__builtin_amdgcn_exp2f)
    return __builtin_amdgcn_exp2f(x);
#else
    return __exp2f(x);
#endif
}
__device__ __forceinline__ float flog2(float x) {
#if __has_builtin(__builtin_amdgcn_logf)
    return __builtin_amdgcn_logf(x);
#else
    return __log2f(x);
#endif
}

#define RF(x) __int_as_float(__builtin_amdgcn_readfirstlane(__float_as_int(x)))

// cross-half (lanes 0-31 <-> 32-63) exchange; semantics-agnostic select (verified r1/r2).
__device__ __forceinline__ float xswap32(float x) {
#ifdef HAVE_PLSWAP
    int xi = __float_as_int(x);
    auto pr = __builtin_amdgcn_permlane32_swap(xi, xi, false, false);
    int r0 = ((const int*)&pr)[0];
    int r1 = ((const int*)&pr)[1];
    return (r0 == xi) ? __int_as_float(r1) : __int_as_float(r0);
#else
    return __shfl_xor(x, 32);
#endif
}

// row exchange lanes l <-> l^16
__device__ __forceinline__ float xswap16(float x) {
#ifdef HAVE_PL16
    int xi = __float_as_int(x);
    auto pr = __builtin_amdgcn_permlane16_swap(xi, xi, false, false);
    int r0 = ((const int*)&pr)[0];
    int r1 = ((const int*)&pr)[1];
    return (r0 == xi) ? __int_as_float(r1) : __int_as_float(r0);
#else
    return __shfl_xor(x, 16);
#endif
}

// XOR-symmetric DPP patterns: 0xB1=xor1, 0x4E=xor2, 0x1B=xor3, 0x141=xor7, 0x140=xor15
#define DPPF(dst, src, CTRL) \
    dst = __int_as_float(__builtin_amdgcn_update_dpp(0, __float_as_int(src), (CTRL), 0xF, 0xF, 1))

// ---------------- setup: tiny, 1 block x 64 ----------------
__global__ void smm_setup(const float* __restrict__ plr,
                          const float* __restrict__ mu,
                          const float* __restrict__ cov,
                          const float* __restrict__ tl,
                          const float* __restrict__ il) {
    int l = threadIdx.x;
    __shared__ float red[64];
    __shared__ float redp[64];
    __shared__ float muP[32];
    __shared__ float constc_s;
    float cd = cov[l * 64 + l];
    float pd = 1.0f / cd;
    red[l] = logf(cd);
    redp[l] = pd;
    __syncthreads();
    if (l == 0) {
        float s = 0.f;
        for (int i = 0; i < 64; ++i) s += red[i];
        constc_s = 64.0f * logf(2.0f * 3.14159265358979323846f) + s;
    }
    __syncthreads();
    float constc = constc_s;

    g_p2[l] = 0.5f * L2E * pd;
    for (int c2 = 0; c2 < 32; ++c2)
        g_pmu[c2 * 64 + l] = L2E * pd * mu[c2 * 64 + l];

    if (l < 32) {
        float s = 0.f;
        for (int d2 = 0; d2 < 64; ++d2) {
            float m_ = mu[l * 64 + d2];
            s += m_ * m_ / cov[d2 * 64 + d2];
        }
        g_mc[l] = -0.5f * L2E * (s + constc);
        muP[l] = s;
    }
    for (int idx = l; idx < KK * CC; idx += 64) {
        int k = idx >> 5, c2 = idx & 31;
        float lr = plr[c2];
        g_ls2[idx] = L2E * ((float)(k + 1) * lr - expf(lr) - lgammaf((float)(k + 2)));
    }
    if (l < 32) {
        int from = l;
        float mx = -1e30f;
        for (int to = 0; to < 32; ++to) mx = fmaxf(mx, tl[to * 32 + from]);
        float s = 0.f;
        for (int to = 0; to < 32; ++to) s += expf(tl[to * 32 + from] - mx);
        float inv = 1.0f / s;
        for (int to = 0; to < 32; ++to)
            g_T[to * 32 + from] = expf(tl[to * 32 + from] - mx) * inv;
    }
    if (l == 32) {
        float mx = -1e30f;
        for (int c2 = 0; c2 < 32; ++c2) mx = fmaxf(mx, il[c2]);
        float s = 0.f;
        for (int c2 = 0; c2 < 32; ++c2) s += expf(il[c2] - mx);
        float lse = mx + logf(s);
        for (int c2 = 0; c2 < 32; ++c2) g_init2[c2] = L2E * (il[c2] - lse);
    }
    __syncthreads();
    if (l == 0) {
        // E[emit2] estimate for x ~ N(0,I): -0.5*L2E*(const + tr(P) + mean_c muPmu)
        float trP = 0.f;
        for (int i = 0; i < 64; ++i) trP += redp[i];
        float mm = 0.f;
        for (int c2 = 0; c2 < 32; ++c2) mm += muP[c2];
        mm *= (1.0f / 32.0f);
        g_mb = -0.5f * L2E * (constc + trP + mm);
    }
}

// ------------- emit: emission probs, written transposed as linear factors -------------
__global__ __launch_bounds__(256) void smm_emit(const float* __restrict__ feat) {
    int tid = threadIdx.x;
    int c = tid & 31, tl_ = tid >> 5;
    int t = blockIdx.x * 8 + tl_;
    int b = blockIdx.y;
    const float4* x4 = (const float4*)(feat + ((size_t)b * TT + t) * DD);
    const float4* pm4 = (const float4*)(g_pmu + c * 64);
    const float4* p24 = (const float4*)g_p2;
    float acc = g_mc[c];
#pragma unroll
    for (int i = 0; i < 16; ++i) {
        float4 xv = x4[i], pm = pm4[i], pv = p24[i];
        acc = fmaf(pm.x, xv.x, acc); acc = fmaf(-pv.x * xv.x, xv.x, acc);
        acc = fmaf(pm.y, xv.y, acc); acc = fmaf(-pv.y * xv.y, xv.y, acc);
        acc = fmaf(pm.z, xv.z, acc); acc = fmaf(-pv.z * xv.z, xv.z, acc);
        acc = fmaf(pm.w, xv.w, acc); acc = fmaf(-pv.w * xv.w, xv.w, acc);
    }
    float ev = fexp2(acc - g_mb);
    __shared__ float stage[32][9];
    stage[c][tl_] = ev;
    __syncthreads();
    int c2 = tid >> 3, j = tid & 7;
    int t0 = blockIdx.x * 8;
    int ti = (t0 + j + TT - 1) & (TT - 1);  // e(t) stored at slot t-1; e(0) -> slot TT-1
    g_eT[((size_t)b * 32 + c2) * TPE + ti] = stage[c2][j];
}

// ------------- forward recursion: one wave per b, scaled-probability domain -------------
// State (per lane = class c, two halves split durations d=1..10 / d=11..20):
//   pf   = scaled alpha_t; accf = scaled astar_t
//   z1..z9 = duration slots (z_i = q_i / Pw_i, Pw_i = 2^(lsr[i]-lsr[0])) -> shift = z*sg
//   Wc = d=11 newborn (cross-half); OFF = sum of all d>=2 terms; nu = d=1 factor
//   sg = eT[t]*su : per-class emission factor x uniform rescale 2^(mb-r8)
// Scale control is DEADBEAT (r3 post-mortem: integrator servo has det=1 -> undamped):
// every 4 steps measure err = log2(pf_lane0)+PIN, immediately rescale all state by
// 2^-err, add err to the exact double accumulator refc; r8 is only a slope EMA.
#define STEP(EV, tcur)                                                            \
    {                                                                             \
        float pf = fmaf(accf, nu, OFF);                                           \
        float G1, G2, G3, G7, G15;                                                \
        DPPF(G1, pf, 0xB1); DPPF(G2, pf, 0x4E); DPPF(G3, pf, 0x1B);               \
        DPPF(G7, pf, 0x141); DPPF(G15, pf, 0x140);                                \
        float G4, G5, G6, G8, G12, G13, G14;                                      \
        DPPF(G6, G1, 0x141); DPPF(G5, G2, 0x141); DPPF(G4, G3, 0x141);            \
        DPPF(G8, G7, 0x140); DPPF(G14, G1, 0x140); DPPF(G13, G2, 0x140);          \
        DPPF(G12, G3, 0x140);                                                     \
        float G9, G10, G11;                                                       \
        DPPF(G9, G14, 0x141); DPPF(G10, G13, 0x141); DPPF(G11, G12, 0x141);       \
        float a0 = Tr[0]*pf;   a0 = fmaf(Tr[1],G1,a0);   a0 = fmaf(Tr[2],G2,a0);   a0 = fmaf(Tr[3],G3,a0);    \
        float a1 = Tr[4]*G4;   a1 = fmaf(Tr[5],G5,a1);   a1 = fmaf(Tr[6],G6,a1);   a1 = fmaf(Tr[7],G7,a1);    \
        float a2 = Tr[8]*G8;   a2 = fmaf(Tr[9],G9,a2);   a2 = fmaf(Tr[10],G10,a2); a2 = fmaf(Tr[11],G11,a2);  \
        float a3 = Tr[12]*G12; a3 = fmaf(Tr[13],G13,a3); a3 = fmaf(Tr[14],G14,a3); a3 = fmaf(Tr[15],G15,a3);  \
        float accl = (a0 + a1) + (a2 + a3);                                       \
        float p48 = xswap16(xswap32(accl));                                       \
        float naccf = accl + p48;                                                 \
        pfc = pf;                                                                 \
        if ((tcur) == lenm1) { pfL = pf; refL = refc; }                           \
        float sg = (EV) * su;                                                     \
        float u2 = accf * nu;                                                     \
        float s0 = half ? Wc : u2;                                                \
        float e9 = z9 * sg;                                                       \
        float t9 = e9 * rr;                                                       \
        float x9 = xswap32(t9);                                                   \
        float Wn = half ? x9 : t9;                                                \
        z9 = z8*sg; z8 = z7*sg; z7 = z6*sg; z6 = z5*sg; z5 = z4*sg;               \
        z4 = z3*sg; z3 = z2*sg; z2 = z1*sg; z1 = s0*sg;                           \
        float tA = Pw1*z1; tA = fmaf(Pw2,z2,tA); tA = fmaf(Pw3,z3,tA);            \
        tA = fmaf(Pw4,z4,tA); tA = fmaf(Pw5,z5,tA);                               \
        float tB = Pw6*z6; tB = fmaf(Pw7,z7,tB); tB = fmaf(Pw8,z8,tB);            \
        tB = fmaf(Pw9,z9,tB);                                                     \
        float S = tA + tB;                                                        \
        float Sx = xswap32(S);                                                    \
        OFF = fmaxf((S + Sx) + Wn, 1e-36f);                                       \
        nu = sg * E1;                                                             \
        accf = naccf;                                                             \
        Wc = Wn;                                                                  \
        refc += (double)r8;                                                       \
    }

// deadbeat scale reset + slope EMA. Applied between steps; state prepared for t+1
// is rescaled by 2^-err (accf OR nu, never both: only their product matters).
#define CTRLDB(gain)                                                              \
    {                                                                             \
        float err = flog2(fmaxf(RF(pfc), 1e-37f)) + PIN;                          \
        err = fminf(fmaxf(err, -40.0f), 40.0f);                                   \
        float cs = fexp2(-err);                                                   \
        accf *= cs; OFF *= cs; Wc *= cs;                                          \
        z1*=cs; z2*=cs; z3*=cs; z4*=cs; z5*=cs;                                   \
        z6*=cs; z7*=cs; z8*=cs; z9*=cs;                                           \
        refc += (double)err;                                                      \
        r8 = fmaf(err, (gain), r8);                                               \
        su = fexp2(mb - r8);                                                      \
    }

__global__ __launch_bounds__(64, 1)
void smm_forward(const int* __restrict__ lens, float* __restrict__ out) {
    const int b = blockIdx.x;
    const int l = threadIdx.x;
    const int c = l & 31;
    const int half = l >> 5;
    const int i16 = l & 15;
    const int rb = ((l >> 4) & 1) * 16;
    const int cT = half ? (c ^ 16) : c;

    float lsr[10];
#pragma unroll
    for (int i = 0; i < 10; ++i) lsr[i] = g_ls2[(half * 10 + i) * 32 + c];

    // transition row, permuted for the XOR gather: Tr[j] pairs with p[rb + (i16^j)]
    float Tr[16];
#pragma unroll
    for (int j2 = 0; j2 < 16; ++j2) Tr[j2] = g_T[cT * 32 + rb + (i16 ^ j2)];

    // cross-half duration-score exchange
    float tswp = __shfl_xor(lsr[0], 32);
    float ls1c = half ? tswp : lsr[0];   // d=1 score of this class
    float d11s = half ? lsr[0] : tswp;   // d=11 score of this class

    // constant slot weights (telescoped): Pw_i = 2^(lsr[i]-lsr[0])
    float Pw1 = fexp2(lsr[1] - lsr[0]), Pw2 = fexp2(lsr[2] - lsr[0]);
    float Pw3 = fexp2(lsr[3] - lsr[0]), Pw4 = fexp2(lsr[4] - lsr[0]);
    float Pw5 = fexp2(lsr[5] - lsr[0]), Pw6 = fexp2(lsr[6] - lsr[0]);
    float Pw7 = fexp2(lsr[7] - lsr[0]), Pw8 = fexp2(lsr[8] - lsr[0]);
    float Pw9 = fexp2(lsr[9] - lsr[0]);
    float rr  = fexp2(d11s - lsr[0]);    // exit weight d=10 -> d=11 (half0); 1 at half1
    float E1  = fexp2(ls1c);

    int len = lens[b];
    if (len < 1) len = 1;
    if (len > TT) len = TT;
    const int lenm1 = len - 1;
    int nsteps = (len + 7) & ~7;

    const float* eT = g_eT + ((size_t)b * 32 + c) * TPE;
    const float4* cp = (const float4*)eT;
    float4 cA = cp[0], cB = cp[1], pA = cp[2], pB = cp[3];

    // ---- bootstrap at t=0: alpha(0) = init + ls(d=1) + emit(0) ----
    float mb = g_mb;
    float e0 = eT[TT - 1];
    float iv = g_init2[c] + ls1c;
    float a0v = iv + mb + flog2(fmaxf(e0, 1e-37f));
    float refc0 = RF(a0v);
    double refc = (double)refc0;
    float nu = e0 * fexp2(iv + mb - refc0 - PIN);
    float accf = 1.0f, OFF = 0.0f;
    float z1=0.f,z2=0.f,z3=0.f,z4=0.f,z5=0.f,z6=0.f,z7=0.f,z8=0.f,z9=0.f;
    float Wc = 0.f;
    float r8 = mb;       // per-step scale advance estimate (slope EMA)
    float su = 1.0f;     // 2^(mb - r8)
    float pfL = 0.f, pfc = 0.f;
    double refL = 0.0;

    // ---- prologue block (t=0..7): per-step deadbeat to lock the slope ----
    {
        float4 nA = cp[4], nB = cp[5];
        STEP(cA.x, 0); CTRLDB(0.3f); STEP(cA.y, 1); CTRLDB(0.3f);
        STEP(cA.z, 2); CTRLDB(0.3f); STEP(cA.w, 3); CTRLDB(0.3f);
        STEP(cB.x, 4); CTRLDB(0.3f); STEP(cB.y, 5); CTRLDB(0.3f);
        STEP(cB.z, 6); CTRLDB(0.3f); STEP(cB.w, 7); CTRLDB(0.3f);
        cA = pA; cB = pB; pA = nA; pB = nB;
    }

    for (int tb = 8; tb < nsteps; tb += 8) {
        int bi = tb >> 2;
        float4 nA = cp[bi + 4], nB = cp[bi + 5];   // prefetch t+16..t+23
        STEP(cA.x, tb + 0); STEP(cA.y, tb + 1); STEP(cA.z, tb + 2); STEP(cA.w, tb + 3);
        CTRLDB(0.125f);
        STEP(cB.x, tb + 4); STEP(cB.y, tb + 5); STEP(cB.z, tb + 6); STEP(cB.w, tb + 7);
        CTRLDB(0.125f);
        cA = pA; cB = pB; pA = nA; pB = nB;
    }

    // ---- final LSE over classes: all pfL share scale refL+PIN ----
    float tot = pfL;
#pragma unroll
    for (int st = 1; st < 32; st <<= 1) tot += __shfl_xor(tot, st);
    if (l == 0) {
        double a = refL + (double)PIN + (double)flog2(fmaxf(tot, 1e-37f));
        out[b] = (float)(-0.69314718055994530942 * a);
    }
}

extern "C" void kernel_launch(void* const* d_in, const int* in_sizes, int n_in,
                              void* d_out, int out_size, void* d_ws, size_t ws_size,
                              hipStream_t stream) {
    const float* feat = (const float*)d_in[0];
    const float* plr  = (const float*)d_in[1];
    const float* mu   = (const float*)d_in[2];
    const float* cov  = (const float*)d_in[3];
    const float* tl   = (const float*)d_in[4];
    const float* il   = (const float*)d_in[5];
    const int*   lens = (const int*)d_in[6];
    float* outf = (float*)d_out;
    int B = in_sizes[6];
    if (B > 8) B = 8;  // scratch sized for the problem's B=8

    smm_setup<<<1, 64, 0, stream>>>(plr, mu, cov, tl, il);
    smm_emit<<<dim3(TT / 8, B), 256, 0, stream>>>(feat);
    smm_forward<<<B, 64, 0, stream>>>(lens, outf);
}